// Round 14
// baseline (266.470 us; speedup 1.0000x reference)
//
#include <hip/hip_runtime.h>
#include <math.h>

// Model: B=32, C=64, T=1024, H=10, OUT=2.
// ONE kernel, 32 blocks (one per batch element) x 512 threads; each thread
// owns TWO time-steps (t, t+512). S1 embed | S2 bn+tanh + qkv stats |
// S3 M=KV^T two passes | S4 N=M Wc^T/H, recompute q -> prec=q.N |
// S5 bn+relu -> Iin into LDS | S6 LSNN scan on wave 0 from LDS.
//
// R13 post-mortem: parallel combine bought only 5us (167->162). Occupancy
// counter (1.3% avg vs 3.1% stages / 0.4% scan) implies the SCAN is ~60% of
// the kernel (~90-100us), 4-5x the ballot-chain floor. Cause: one dependent
// ds_read_b32 per step + compiler-conservative s_waitcnt lgkmcnt(0) drains
// the prefetch queue every step (~120cyc LDS latency on the critical path).
// R14: scan slab transposed to [h][1028] (row-contiguous per channel,
// 16B-aligned, stride => <=2-way bank alias = free) -> ONE ds_read_b128 per
// 4 steps, prefetched 8 steps ahead; worst-case drain = 120cyc/8 steps.
// Also: dred2 stride 16->17 (R13's 10752 LDS bank-conflict cycles).

constexpr int B = 32, C = 64, T = 1024, H = 10;
constexpr int NT = 512;   // threads per block (8 waves)
constexpr int RS = 1028;  // scan-row stride (floats): 16B-aligned, ~conflict-free

struct Params {
  const float *beeg, *W_ef, *b_ef, *g_i, *be_i, *Wq, *g_q, *be_q, *Wk, *g_k,
      *be_k, *Wv, *g_v, *be_v, *Wc, *g_c, *be_c, *W_in, *W_rec, *W_cls, *b_cls;
  int* cnt;              // barrier counters (memset 0 each launch)
  double *P1, *P2, *P3;  // cross-block stat partials, layout [ch][32]
  float* out;
};

// DPP wave64 sum: result valid in lane 63 (VALU pipe, no DS traffic).
template <int CTRL>
__device__ inline float dadd(float v) {
  int x = __builtin_amdgcn_update_dpp(0, __float_as_int(v), CTRL, 0xf, 0xf,
                                      true);
  return v + __int_as_float(x);
}
__device__ inline float wred63(float v) {
  v = dadd<0x111>(v);  // row_shr:1
  v = dadd<0x112>(v);  // row_shr:2
  v = dadd<0x114>(v);  // row_shr:4
  v = dadd<0x118>(v);  // row_shr:8
  v = dadd<0x142>(v);  // row_bcast:15
  v = dadd<0x143>(v);  // row_bcast:31
  return v;            // lane 63 = full sum
}

// 32-block barrier, fence-free (all cross-block data via agent-scope atomics).
__device__ inline void gbar(int* cnt, int phase, int tid) {
  __syncthreads();
  if (tid == 0) {
    __hip_atomic_fetch_add(&cnt[phase], 1, __ATOMIC_RELEASE,
                           __HIP_MEMORY_SCOPE_AGENT);
    while (__hip_atomic_load(&cnt[phase], __ATOMIC_RELAXED,
                             __HIP_MEMORY_SCOPE_AGENT) < B)
      __builtin_amdgcn_s_sleep(2);
  }
  __syncthreads();
}

__global__ void __launch_bounds__(NT) fused11(Params p) {
  const int b = blockIdx.x, tid = threadIdx.x;
  const int lane = tid & 63, wid = tid >> 6;   // 8 waves
  const int t0 = tid, t1 = tid + NT;

  // LDS ~58.5KB => 2 WGs/CU by the occupancy heuristic => 4 waves/EU
  // => 128-VGPR budget (keeps the no-spill regime of R8-R13).
  __shared__ __align__(16) float slab[T * 11];   // scratch, then Iin [h][RS]
  __shared__ __align__(16) float gtab[T];        // 4KB
  __shared__ double dred2[60 * 17 + 4];          // combine partials (pad 17)
  __shared__ double dtot[60];
  __shared__ float stM[30], stI[30], Ms[100], Nl[100];

  float* swred = slab;         // [8][60] stats scratch (dead before S5)
  float* mpw   = slab + 512;   // [8][100] M partials (dead before S5)

  // g[t] = (9(1-0.9^{T-t}) - 4(1-0.8^{T-t})) / T  (f32 closed form)
  {
    const float L2A = -0.15200309344504995f;   // log2(0.9)
    const float L2D = -0.32192809488736235f;   // log2(0.8)
    float m0 = (float)(T - t0), m1 = (float)(T - t1);
    gtab[t0] = (9.0f * (1.0f - exp2f(m0 * L2A)) -
                4.0f * (1.0f - exp2f(m0 * L2D))) * (1.0f / (float)T);
    gtab[t1] = (9.0f * (1.0f - exp2f(m1 * L2A)) -
                4.0f * (1.0f - exp2f(m1 * L2D))) * (1.0f / (float)T);
  }

  // parallel stats combine: P layout [ch][32]; ch x 16 workers, 2 loads each.
  auto combine = [&](double* P, int Q2) {
    for (int id = tid; id < Q2 * 16; id += NT) {
      int ch = id >> 4, i = id & 15;
      double s = __hip_atomic_load(&P[ch * 32 + i], __ATOMIC_RELAXED,
                                   __HIP_MEMORY_SCOPE_AGENT) +
                 __hip_atomic_load(&P[ch * 32 + 16 + i], __ATOMIC_RELAXED,
                                   __HIP_MEMORY_SCOPE_AGENT);
      dred2[ch * 17 + i] = s;
    }
    __syncthreads();
    if (tid < Q2) {
      double s = 0.0;
#pragma unroll
      for (int i = 0; i < 16; ++i) s += dred2[tid * 17 + i];
      dtot[tid] = s;
    }
    __syncthreads();
  };

  // ---------------- S1: embed (weights via uniform/scalar loads)
  float p1a[H], p1b[H];
#pragma unroll
  for (int h = 0; h < H; ++h) { p1a[h] = p.b_ef[h]; p1b[h] = p.b_ef[h]; }
  {
    const float* bp = p.beeg + (size_t)b * C * T;
#pragma unroll 8
    for (int c = 0; c < C; ++c) {
      float va = bp[(size_t)c * T + t0];
      float vb = bp[(size_t)c * T + t1];
#pragma unroll
      for (int h = 0; h < H; ++h) {
        float w = p.W_ef[h * C + c];   // wave-uniform -> s_load
        p1a[h] = fmaf(va, w, p1a[h]);
        p1b[h] = fmaf(vb, w, p1b[h]);
      }
    }
  }
#pragma unroll
  for (int h = 0; h < H; ++h) {
    float r1 = wred63(p1a[h] + p1b[h]);
    float r2 = wred63(p1a[h] * p1a[h] + p1b[h] * p1b[h]);
    if (lane == 63) { swred[wid * 60 + h] = r1; swred[wid * 60 + 10 + h] = r2; }
  }
  __syncthreads();
  if (tid < 20) {
    float s = 0.f;
#pragma unroll
    for (int w = 0; w < 8; ++w) s += swred[w * 60 + tid];
    __hip_atomic_store(&p.P1[tid * 32 + b], (double)s, __ATOMIC_RELAXED,
                       __HIP_MEMORY_SCOPE_AGENT);
  }
  gbar(p.cnt, 0, tid);
  combine(p.P1, 20);
  if (tid < 10) {
    double mean = dtot[tid] * (1.0 / 32768.0);
    double var  = dtot[10 + tid] * (1.0 / 32768.0) - mean * mean;
    stM[tid] = (float)mean;
    stI[tid] = (float)(1.0 / sqrt(var + 1e-5));
  }
  __syncthreads();

  // ---------------- S2: x = tanh(bn(pre1)); qkv stats (accumulators only)
  float xa[H], xb[H];
#pragma unroll
  for (int j = 0; j < H; ++j) {
    xa[j] = tanhf(p.g_i[j] * (p1a[j] - stM[j]) * stI[j] + p.be_i[j]);
    xb[j] = tanhf(p.g_i[j] * (p1b[j] - stM[j]) * stI[j] + p.be_i[j]);
  }
  // p1a/p1b dead; only xa/xb (20 floats) persist from here on.
#pragma unroll
  for (int h = 0; h < H; ++h) {
    float qa = 0.f, qb = 0.f, ka = 0.f, kb = 0.f, va = 0.f, vb = 0.f;
#pragma unroll
    for (int j = 0; j < H; ++j) {
      float wq = p.Wq[h * H + j], wk = p.Wk[h * H + j], wv = p.Wv[h * H + j];
      qa = fmaf(xa[j], wq, qa); qb = fmaf(xb[j], wq, qb);
      ka = fmaf(xa[j], wk, ka); kb = fmaf(xb[j], wk, kb);
      va = fmaf(xa[j], wv, va); vb = fmaf(xb[j], wv, vb);
    }
    float r1 = wred63(qa + qb), r2 = wred63(qa * qa + qb * qb);
    float r3 = wred63(ka + kb), r4 = wred63(ka * ka + kb * kb);
    float r5 = wred63(va + vb), r6 = wred63(va * va + vb * vb);
    if (lane == 63) {
      swred[wid * 60 + h]      = r1; swred[wid * 60 + 30 + h] = r2;
      swred[wid * 60 + 10 + h] = r3; swred[wid * 60 + 40 + h] = r4;
      swred[wid * 60 + 20 + h] = r5; swred[wid * 60 + 50 + h] = r6;
    }
  }
  __syncthreads();
  if (tid < 60) {
    float s = 0.f;
#pragma unroll
    for (int w = 0; w < 8; ++w) s += swred[w * 60 + tid];
    __hip_atomic_store(&p.P2[tid * 32 + b], (double)s, __ATOMIC_RELAXED,
                       __HIP_MEMORY_SCOPE_AGENT);
  }
  gbar(p.cnt, 1, tid);
  combine(p.P2, 60);
  if (tid < 30) {
    double mean = dtot[tid] * (1.0 / 32768.0);
    double var  = dtot[30 + tid] * (1.0 / 32768.0) - mean * mean;
    stM[tid] = (float)mean;
    stI[tid] = (float)(1.0 / sqrt(var + 1e-5));
  }
  __syncthreads();

  // ---------------- S3: M = KV^T in two sequential passes (low pressure)
  {  // pass a
    float kx[H], vx[H];
#pragma unroll
    for (int h = 0; h < H; ++h) {
      float ka = 0.f, va = 0.f;
#pragma unroll
      for (int j = 0; j < H; ++j) {
        ka = fmaf(xa[j], p.Wk[h * H + j], ka);
        va = fmaf(xa[j], p.Wv[h * H + j], va);
      }
      kx[h] = fmaxf(p.g_k[h] * (ka - stM[10 + h]) * stI[10 + h] + p.be_k[h], 0.f);
      vx[h] = tanhf(p.g_v[h] * (va - stM[20 + h]) * stI[20 + h] + p.be_v[h]);
    }
#pragma unroll
    for (int i = 0; i < H; ++i)
#pragma unroll
      for (int j = 0; j < H; ++j) {
        float r = wred63(kx[i] * vx[j]);
        if (lane == 63) mpw[wid * 100 + i * 10 + j] = r;
      }
  }
  {  // pass b (accumulate)
    float kx[H], vx[H];
#pragma unroll
    for (int h = 0; h < H; ++h) {
      float kb = 0.f, vb = 0.f;
#pragma unroll
      for (int j = 0; j < H; ++j) {
        kb = fmaf(xb[j], p.Wk[h * H + j], kb);
        vb = fmaf(xb[j], p.Wv[h * H + j], vb);
      }
      kx[h] = fmaxf(p.g_k[h] * (kb - stM[10 + h]) * stI[10 + h] + p.be_k[h], 0.f);
      vx[h] = tanhf(p.g_v[h] * (vb - stM[20 + h]) * stI[20 + h] + p.be_v[h]);
    }
#pragma unroll
    for (int i = 0; i < H; ++i)
#pragma unroll
      for (int j = 0; j < H; ++j) {
        float r = wred63(kx[i] * vx[j]);
        if (lane == 63) mpw[wid * 100 + i * 10 + j] += r;
      }
  }
  __syncthreads();
  if (tid < 100) {
    float s = 0.f;
#pragma unroll
    for (int w = 0; w < 8; ++w) s += mpw[w * 100 + tid];
    Ms[tid] = s;
  }
  __syncthreads();

  // ---------------- S4: N = (M Wc^T)/H; recompute q; prec = q . N
  if (tid < 100) {
    int i = tid / 10, h = tid % 10;
    float a = 0.f;
#pragma unroll
    for (int j = 0; j < H; ++j) a = fmaf(Ms[i * 10 + j], p.Wc[h * H + j], a);
    Nl[tid] = a * 0.1f;
  }
  __syncthreads();
  float pca[H], pcb[H];
  {  // pass a
    float qv[H];
#pragma unroll
    for (int h = 0; h < H; ++h) {
      float qa = 0.f;
#pragma unroll
      for (int j = 0; j < H; ++j) qa = fmaf(xa[j], p.Wq[h * H + j], qa);
      qv[h] = fmaxf(p.g_q[h] * (qa - stM[h]) * stI[h] + p.be_q[h], 0.f);
    }
#pragma unroll
    for (int h = 0; h < H; ++h) {
      float a = 0.f;
#pragma unroll
      for (int i = 0; i < H; ++i) a = fmaf(qv[i], Nl[i * 10 + h], a);
      pca[h] = a;
    }
  }
  {  // pass b
    float qv[H];
#pragma unroll
    for (int h = 0; h < H; ++h) {
      float qb = 0.f;
#pragma unroll
      for (int j = 0; j < H; ++j) qb = fmaf(xb[j], p.Wq[h * H + j], qb);
      qv[h] = fmaxf(p.g_q[h] * (qb - stM[h]) * stI[h] + p.be_q[h], 0.f);
    }
#pragma unroll
    for (int h = 0; h < H; ++h) {
      float a = 0.f;
#pragma unroll
      for (int i = 0; i < H; ++i) a = fmaf(qv[i], Nl[i * 10 + h], a);
      pcb[h] = a;
    }
  }
  // xa/xb dead now; pca/pcb (20 floats) live.
#pragma unroll
  for (int h = 0; h < H; ++h) {
    float r1 = wred63(pca[h] + pcb[h]);
    float r2 = wred63(pca[h] * pca[h] + pcb[h] * pcb[h]);
    if (lane == 63) { swred[wid * 60 + h] = r1; swred[wid * 60 + 10 + h] = r2; }
  }
  __syncthreads();
  if (tid < 20) {
    float s = 0.f;
#pragma unroll
    for (int w = 0; w < 8; ++w) s += swred[w * 60 + tid];
    __hip_atomic_store(&p.P3[tid * 32 + b], (double)s, __ATOMIC_RELAXED,
                       __HIP_MEMORY_SCOPE_AGENT);
  }
  gbar(p.cnt, 2, tid);
  combine(p.P3, 20);
  if (tid < 10) {
    double mean = dtot[tid] * (1.0 / 32768.0);
    double var  = dtot[10 + tid] * (1.0 / 32768.0) - mean * mean;
    stM[tid] = (float)mean;
    stI[tid] = (float)(1.0 / sqrt(var + 1e-5));
  }
  __syncthreads();   // all slab-scratch reads done before S5 overwrites

  // ---------------- S5: bn+relu, Iin into LDS rows [h][RS]
  {
    float ca[H];
#pragma unroll
    for (int j = 0; j < H; ++j)
      ca[j] = fmaxf(p.g_c[j] * (pca[j] - stM[j]) * stI[j] + p.be_c[j], 0.f);
#pragma unroll
    for (int h = 0; h < H; ++h) {
      float a = 0.f;
#pragma unroll
      for (int j = 0; j < H; ++j) a = fmaf(ca[j], p.W_in[h * H + j], a);
      slab[h * RS + t0] = a;
    }
#pragma unroll
    for (int j = 0; j < H; ++j)
      ca[j] = fmaxf(p.g_c[j] * (pcb[j] - stM[j]) * stI[j] + p.be_c[j], 0.f);
#pragma unroll
    for (int h = 0; h < H; ++h) {
      float a = 0.f;
#pragma unroll
      for (int j = 0; j < H; ++j) a = fmaf(ca[j], p.W_in[h * H + j], a);
      slab[h * RS + t1] = a;
    }
  }
  __syncthreads();

  // ---------------- S6: LSNN scan, wave 0 only; b128 row reads (4 steps/DS)
  if (tid < 64) {
    // gtot closed form: .9^1024/.8^1024 underflow -> (5*1024 - 81 + 16)/1024
    const float gtot = 4.9365234375f;

    const int slot = lane < H ? lane : 0;   // inactive lanes broadcast row 0
    const float* row = slab + slot * RS;
    float wr[H];
#pragma unroll
    for (int j = 0; j < H; ++j)
      wr[j] = (lane < H) ? p.W_rec[lane * H + j] : 0.f;  // one-time global

    float cur = 0.f, vm = 0.f, S = 0.f;
    unsigned zm = 0u;

    auto step = [&](float iin, float gt) {
      float p01 = (((zm >> 0) & 1u) ? wr[0] : 0.f) + (((zm >> 1) & 1u) ? wr[1] : 0.f);
      float p23 = (((zm >> 2) & 1u) ? wr[2] : 0.f) + (((zm >> 3) & 1u) ? wr[3] : 0.f);
      float p45 = (((zm >> 4) & 1u) ? wr[4] : 0.f) + (((zm >> 5) & 1u) ? wr[5] : 0.f);
      float p67 = (((zm >> 6) & 1u) ? wr[6] : 0.f) + (((zm >> 7) & 1u) ? wr[7] : 0.f);
      float p89 = (((zm >> 8) & 1u) ? wr[8] : 0.f) + (((zm >> 9) & 1u) ? wr[9] : 0.f);
      float rec = ((p01 + p23) + (p45 + p67)) + p89;
      float i_jump = (cur + iin) + rec;
      float v_dec = fmaf(0.1f, i_jump - vm, vm);  // vm + 0.1*(i_jump - vm)
      cur = 0.8f * i_jump;                        // i_dec
      bool z = v_dec > 0.5f;
      vm = z ? 0.f : v_dec;
      S += z ? gt : 0.f;
      zm = (unsigned)__ballot(z) & 0x3FFu;
    };

    float4 iA = *(const float4*)&row[0];
    float4 iB = *(const float4*)&row[4];
    float4 gA = *(const float4*)&gtab[0], gB = *(const float4*)&gtab[4];

    for (int t8 = 0; t8 < T - 8; t8 += 8) {
      float4 iN1 = *(const float4*)&row[t8 + 8];
      float4 iN2 = *(const float4*)&row[t8 + 12];
      float4 gN1 = *(const float4*)&gtab[t8 + 8];
      float4 gN2 = *(const float4*)&gtab[t8 + 12];
      step(iA.x, gA.x); step(iA.y, gA.y); step(iA.z, gA.z); step(iA.w, gA.w);
      step(iB.x, gB.x); step(iB.y, gB.y); step(iB.z, gB.z); step(iB.w, gB.w);
      iA = iN1; iB = iN2; gA = gN1; gB = gN2;
    }
    step(iA.x, gA.x); step(iA.y, gA.y); step(iA.z, gA.z); step(iA.w, gA.w);
    step(iB.x, gB.x); step(iB.y, gB.y); step(iB.z, gB.z); step(iB.w, gB.w);

    int li = lane < H ? lane : 0;
    float c0 = (lane < H) ? S * p.W_cls[li]     : 0.f;
    float c1 = (lane < H) ? S * p.W_cls[H + li] : 0.f;
    float r0 = wred63(c0), r1 = wred63(c1);
    if (lane == 63) {
      p.out[b * 2 + 0] = r0 + gtot * p.b_cls[0];
      p.out[b * 2 + 1] = r1 + gtot * p.b_cls[1];
    }
  }
}

extern "C" void kernel_launch(void* const* d_in, const int* in_sizes, int n_in,
                              void* d_out, int out_size, void* d_ws, size_t ws_size,
                              hipStream_t stream) {
  Params p;
  p.beeg  = (const float*)d_in[2];
  p.W_ef  = (const float*)d_in[4];
  p.b_ef  = (const float*)d_in[5];
  p.g_i   = (const float*)d_in[6];
  p.be_i  = (const float*)d_in[7];
  p.Wq    = (const float*)d_in[8];
  p.g_q   = (const float*)d_in[9];
  p.be_q  = (const float*)d_in[10];
  p.Wk    = (const float*)d_in[11];
  p.g_k   = (const float*)d_in[12];
  p.be_k  = (const float*)d_in[13];
  p.Wv    = (const float*)d_in[14];
  p.g_v   = (const float*)d_in[15];
  p.be_v  = (const float*)d_in[16];
  p.Wc    = (const float*)d_in[17];
  p.g_c   = (const float*)d_in[18];
  p.be_c  = (const float*)d_in[19];
  p.W_in  = (const float*)d_in[20];
  p.W_rec = (const float*)d_in[21];
  p.W_cls = (const float*)d_in[22];
  p.b_cls = (const float*)d_in[23];

  char* ws = (char*)d_ws;
  p.cnt = (int*)ws;                            // 3 counters, memset below
  p.P1  = (double*)(ws + 256);                 // [20][32] doubles
  p.P2  = (double*)(ws + 256 + 5120);          // [60][32] doubles
  p.P3  = (double*)(ws + 256 + 5120 + 15360);  // [20][32] doubles
  p.out = (float*)d_out;

  (void)hipMemsetAsync(d_ws, 0, 256, stream);  // zero barrier counters
  fused11<<<dim3(B), dim3(NT), 0, stream>>>(p);
}

// Round 15
// 263.689 us; speedup vs baseline: 1.0105x; 1.0105x over previous
//
#include <hip/hip_runtime.h>
#include <math.h>

// Model: B=32, C=64, T=1024, H=10, OUT=2.
// ONE kernel, 32 blocks (one per batch element) x 512 threads; each thread
// owns TWO time-steps (t, t+512). S1 embed | S2 bn+tanh + qkv stats |
// S3 M=KV^T two passes | S4 N=M Wc^T/H, recompute q -> prec=q.N |
// S5 bn+relu -> Iin into LDS | S6 LSNN scan on wave 0 from LDS.
//
// R14 post-mortem: b128 scan reads were NEUTRAL (162->164us) -- scan LDS
// latency was never the limiter. Occupancy arithmetic (avg 110 resident
// waves = 0.35x256 + 0.65x32) says the scan is ~100us: ISSUE-bound. The
// compiled select `(zm>>j)&1 ? wr[j] : 0` needs a 64-bit mask pair per bit
// (s_lshr+s_and+s_cmp+s_cselect_b64+v_cndmask) -> ~95-150 issue cyc/step
// + vcc hazards ~= the observed ~235 cyc/step.
// R15: sign-extend/AND trick: b = -((lo>>j)&1) (one SALU, 0 or -1) then
// v_and_b32 with the pre-bitcast weight + v_add. No mask pairs, no
// cndmask in the recurrent dot. Bit-identical math (+0.0f add). Step body
// ~10 SALU + ~22 VALU -> predict scan ~100 -> ~35-50us.

constexpr int B = 32, C = 64, T = 1024, H = 10;
constexpr int NT = 512;   // threads per block (8 waves)
constexpr int RS = 1028;  // scan-row stride (floats): 16B-aligned

struct Params {
  const float *beeg, *W_ef, *b_ef, *g_i, *be_i, *Wq, *g_q, *be_q, *Wk, *g_k,
      *be_k, *Wv, *g_v, *be_v, *Wc, *g_c, *be_c, *W_in, *W_rec, *W_cls, *b_cls;
  int* cnt;              // barrier counters (memset 0 each launch)
  double *P1, *P2, *P3;  // cross-block stat partials, layout [ch][32]
  float* out;
};

// DPP wave64 sum: result valid in lane 63 (VALU pipe, no DS traffic).
template <int CTRL>
__device__ inline float dadd(float v) {
  int x = __builtin_amdgcn_update_dpp(0, __float_as_int(v), CTRL, 0xf, 0xf,
                                      true);
  return v + __int_as_float(x);
}
__device__ inline float wred63(float v) {
  v = dadd<0x111>(v);  // row_shr:1
  v = dadd<0x112>(v);  // row_shr:2
  v = dadd<0x114>(v);  // row_shr:4
  v = dadd<0x118>(v);  // row_shr:8
  v = dadd<0x142>(v);  // row_bcast:15
  v = dadd<0x143>(v);  // row_bcast:31
  return v;            // lane 63 = full sum
}

// 32-block barrier, fence-free (all cross-block data via agent-scope atomics).
__device__ inline void gbar(int* cnt, int phase, int tid) {
  __syncthreads();
  if (tid == 0) {
    __hip_atomic_fetch_add(&cnt[phase], 1, __ATOMIC_RELEASE,
                           __HIP_MEMORY_SCOPE_AGENT);
    while (__hip_atomic_load(&cnt[phase], __ATOMIC_RELAXED,
                             __HIP_MEMORY_SCOPE_AGENT) < B)
      __builtin_amdgcn_s_sleep(2);
  }
  __syncthreads();
}

// masked weight: bit j of m (uniform) ? w : +0.0f, via sign-extend + AND.
__device__ inline float maskf(unsigned m, int j, int wbits) {
  int b = -(int)((m >> j) & 1u);          // 0 or 0xFFFFFFFF (SALU on uniform)
  return __int_as_float(b & wbits);       // v_and_b32 (sgpr & vgpr)
}

__global__ void __launch_bounds__(NT) fused12(Params p) {
  const int b = blockIdx.x, tid = threadIdx.x;
  const int lane = tid & 63, wid = tid >> 6;   // 8 waves
  const int t0 = tid, t1 = tid + NT;

  // LDS ~58.5KB => 2 WGs/CU by the occupancy heuristic => 4 waves/EU
  // => 128-VGPR budget (keeps the no-spill regime of R8-R14).
  __shared__ __align__(16) float slab[T * 11];   // scratch, then Iin [h][RS]
  __shared__ __align__(16) float gtab[T];        // 4KB
  __shared__ double dred2[60 * 17 + 4];          // combine partials (pad 17)
  __shared__ double dtot[60];
  __shared__ float stM[30], stI[30], Ms[100], Nl[100];

  float* swred = slab;         // [8][60] stats scratch (dead before S5)
  float* mpw   = slab + 512;   // [8][100] M partials (dead before S5)

  // g[t] = (9(1-0.9^{T-t}) - 4(1-0.8^{T-t})) / T  (f32 closed form)
  {
    const float L2A = -0.15200309344504995f;   // log2(0.9)
    const float L2D = -0.32192809488736235f;   // log2(0.8)
    float m0 = (float)(T - t0), m1 = (float)(T - t1);
    gtab[t0] = (9.0f * (1.0f - exp2f(m0 * L2A)) -
                4.0f * (1.0f - exp2f(m0 * L2D))) * (1.0f / (float)T);
    gtab[t1] = (9.0f * (1.0f - exp2f(m1 * L2A)) -
                4.0f * (1.0f - exp2f(m1 * L2D))) * (1.0f / (float)T);
  }

  // parallel stats combine: P layout [ch][32]; ch x 16 workers, 2 loads each.
  auto combine = [&](double* P, int Q2) {
    for (int id = tid; id < Q2 * 16; id += NT) {
      int ch = id >> 4, i = id & 15;
      double s = __hip_atomic_load(&P[ch * 32 + i], __ATOMIC_RELAXED,
                                   __HIP_MEMORY_SCOPE_AGENT) +
                 __hip_atomic_load(&P[ch * 32 + 16 + i], __ATOMIC_RELAXED,
                                   __HIP_MEMORY_SCOPE_AGENT);
      dred2[ch * 17 + i] = s;
    }
    __syncthreads();
    if (tid < Q2) {
      double s = 0.0;
#pragma unroll
      for (int i = 0; i < 16; ++i) s += dred2[tid * 17 + i];
      dtot[tid] = s;
    }
    __syncthreads();
  };

  // ---------------- S1: embed (weights via uniform/scalar loads)
  float p1a[H], p1b[H];
#pragma unroll
  for (int h = 0; h < H; ++h) { p1a[h] = p.b_ef[h]; p1b[h] = p.b_ef[h]; }
  {
    const float* bp = p.beeg + (size_t)b * C * T;
#pragma unroll 8
    for (int c = 0; c < C; ++c) {
      float va = bp[(size_t)c * T + t0];
      float vb = bp[(size_t)c * T + t1];
#pragma unroll
      for (int h = 0; h < H; ++h) {
        float w = p.W_ef[h * C + c];   // wave-uniform -> s_load
        p1a[h] = fmaf(va, w, p1a[h]);
        p1b[h] = fmaf(vb, w, p1b[h]);
      }
    }
  }
#pragma unroll
  for (int h = 0; h < H; ++h) {
    float r1 = wred63(p1a[h] + p1b[h]);
    float r2 = wred63(p1a[h] * p1a[h] + p1b[h] * p1b[h]);
    if (lane == 63) { swred[wid * 60 + h] = r1; swred[wid * 60 + 10 + h] = r2; }
  }
  __syncthreads();
  if (tid < 20) {
    float s = 0.f;
#pragma unroll
    for (int w = 0; w < 8; ++w) s += swred[w * 60 + tid];
    __hip_atomic_store(&p.P1[tid * 32 + b], (double)s, __ATOMIC_RELAXED,
                       __HIP_MEMORY_SCOPE_AGENT);
  }
  gbar(p.cnt, 0, tid);
  combine(p.P1, 20);
  if (tid < 10) {
    double mean = dtot[tid] * (1.0 / 32768.0);
    double var  = dtot[10 + tid] * (1.0 / 32768.0) - mean * mean;
    stM[tid] = (float)mean;
    stI[tid] = (float)(1.0 / sqrt(var + 1e-5));
  }
  __syncthreads();

  // ---------------- S2: x = tanh(bn(pre1)); qkv stats (accumulators only)
  float xa[H], xb[H];
#pragma unroll
  for (int j = 0; j < H; ++j) {
    xa[j] = tanhf(p.g_i[j] * (p1a[j] - stM[j]) * stI[j] + p.be_i[j]);
    xb[j] = tanhf(p.g_i[j] * (p1b[j] - stM[j]) * stI[j] + p.be_i[j]);
  }
  // p1a/p1b dead; only xa/xb (20 floats) persist from here on.
#pragma unroll
  for (int h = 0; h < H; ++h) {
    float qa = 0.f, qb = 0.f, ka = 0.f, kb = 0.f, va = 0.f, vb = 0.f;
#pragma unroll
    for (int j = 0; j < H; ++j) {
      float wq = p.Wq[h * H + j], wk = p.Wk[h * H + j], wv = p.Wv[h * H + j];
      qa = fmaf(xa[j], wq, qa); qb = fmaf(xb[j], wq, qb);
      ka = fmaf(xa[j], wk, ka); kb = fmaf(xb[j], wk, kb);
      va = fmaf(xa[j], wv, va); vb = fmaf(xb[j], wv, vb);
    }
    float r1 = wred63(qa + qb), r2 = wred63(qa * qa + qb * qb);
    float r3 = wred63(ka + kb), r4 = wred63(ka * ka + kb * kb);
    float r5 = wred63(va + vb), r6 = wred63(va * va + vb * vb);
    if (lane == 63) {
      swred[wid * 60 + h]      = r1; swred[wid * 60 + 30 + h] = r2;
      swred[wid * 60 + 10 + h] = r3; swred[wid * 60 + 40 + h] = r4;
      swred[wid * 60 + 20 + h] = r5; swred[wid * 60 + 50 + h] = r6;
    }
  }
  __syncthreads();
  if (tid < 60) {
    float s = 0.f;
#pragma unroll
    for (int w = 0; w < 8; ++w) s += swred[w * 60 + tid];
    __hip_atomic_store(&p.P2[tid * 32 + b], (double)s, __ATOMIC_RELAXED,
                       __HIP_MEMORY_SCOPE_AGENT);
  }
  gbar(p.cnt, 1, tid);
  combine(p.P2, 60);
  if (tid < 30) {
    double mean = dtot[tid] * (1.0 / 32768.0);
    double var  = dtot[30 + tid] * (1.0 / 32768.0) - mean * mean;
    stM[tid] = (float)mean;
    stI[tid] = (float)(1.0 / sqrt(var + 1e-5));
  }
  __syncthreads();

  // ---------------- S3: M = KV^T in two sequential passes (low pressure)
  {  // pass a
    float kx[H], vx[H];
#pragma unroll
    for (int h = 0; h < H; ++h) {
      float ka = 0.f, va = 0.f;
#pragma unroll
      for (int j = 0; j < H; ++j) {
        ka = fmaf(xa[j], p.Wk[h * H + j], ka);
        va = fmaf(xa[j], p.Wv[h * H + j], va);
      }
      kx[h] = fmaxf(p.g_k[h] * (ka - stM[10 + h]) * stI[10 + h] + p.be_k[h], 0.f);
      vx[h] = tanhf(p.g_v[h] * (va - stM[20 + h]) * stI[20 + h] + p.be_v[h]);
    }
#pragma unroll
    for (int i = 0; i < H; ++i)
#pragma unroll
      for (int j = 0; j < H; ++j) {
        float r = wred63(kx[i] * vx[j]);
        if (lane == 63) mpw[wid * 100 + i * 10 + j] = r;
      }
  }
  {  // pass b (accumulate)
    float kx[H], vx[H];
#pragma unroll
    for (int h = 0; h < H; ++h) {
      float kb = 0.f, vb = 0.f;
#pragma unroll
      for (int j = 0; j < H; ++j) {
        kb = fmaf(xb[j], p.Wk[h * H + j], kb);
        vb = fmaf(xb[j], p.Wv[h * H + j], vb);
      }
      kx[h] = fmaxf(p.g_k[h] * (kb - stM[10 + h]) * stI[10 + h] + p.be_k[h], 0.f);
      vx[h] = tanhf(p.g_v[h] * (vb - stM[20 + h]) * stI[20 + h] + p.be_v[h]);
    }
#pragma unroll
    for (int i = 0; i < H; ++i)
#pragma unroll
      for (int j = 0; j < H; ++j) {
        float r = wred63(kx[i] * vx[j]);
        if (lane == 63) mpw[wid * 100 + i * 10 + j] += r;
      }
  }
  __syncthreads();
  if (tid < 100) {
    float s = 0.f;
#pragma unroll
    for (int w = 0; w < 8; ++w) s += mpw[w * 100 + tid];
    Ms[tid] = s;
  }
  __syncthreads();

  // ---------------- S4: N = (M Wc^T)/H; recompute q; prec = q . N
  if (tid < 100) {
    int i = tid / 10, h = tid % 10;
    float a = 0.f;
#pragma unroll
    for (int j = 0; j < H; ++j) a = fmaf(Ms[i * 10 + j], p.Wc[h * H + j], a);
    Nl[tid] = a * 0.1f;
  }
  __syncthreads();
  float pca[H], pcb[H];
  {  // pass a
    float qv[H];
#pragma unroll
    for (int h = 0; h < H; ++h) {
      float qa = 0.f;
#pragma unroll
      for (int j = 0; j < H; ++j) qa = fmaf(xa[j], p.Wq[h * H + j], qa);
      qv[h] = fmaxf(p.g_q[h] * (qa - stM[h]) * stI[h] + p.be_q[h], 0.f);
    }
#pragma unroll
    for (int h = 0; h < H; ++h) {
      float a = 0.f;
#pragma unroll
      for (int i = 0; i < H; ++i) a = fmaf(qv[i], Nl[i * 10 + h], a);
      pca[h] = a;
    }
  }
  {  // pass b
    float qv[H];
#pragma unroll
    for (int h = 0; h < H; ++h) {
      float qb = 0.f;
#pragma unroll
      for (int j = 0; j < H; ++j) qb = fmaf(xb[j], p.Wq[h * H + j], qb);
      qv[h] = fmaxf(p.g_q[h] * (qb - stM[h]) * stI[h] + p.be_q[h], 0.f);
    }
#pragma unroll
    for (int h = 0; h < H; ++h) {
      float a = 0.f;
#pragma unroll
      for (int i = 0; i < H; ++i) a = fmaf(qv[i], Nl[i * 10 + h], a);
      pcb[h] = a;
    }
  }
  // xa/xb dead now; pca/pcb (20 floats) live.
#pragma unroll
  for (int h = 0; h < H; ++h) {
    float r1 = wred63(pca[h] + pcb[h]);
    float r2 = wred63(pca[h] * pca[h] + pcb[h] * pcb[h]);
    if (lane == 63) { swred[wid * 60 + h] = r1; swred[wid * 60 + 10 + h] = r2; }
  }
  __syncthreads();
  if (tid < 20) {
    float s = 0.f;
#pragma unroll
    for (int w = 0; w < 8; ++w) s += swred[w * 60 + tid];
    __hip_atomic_store(&p.P3[tid * 32 + b], (double)s, __ATOMIC_RELAXED,
                       __HIP_MEMORY_SCOPE_AGENT);
  }
  gbar(p.cnt, 2, tid);
  combine(p.P3, 20);
  if (tid < 10) {
    double mean = dtot[tid] * (1.0 / 32768.0);
    double var  = dtot[10 + tid] * (1.0 / 32768.0) - mean * mean;
    stM[tid] = (float)mean;
    stI[tid] = (float)(1.0 / sqrt(var + 1e-5));
  }
  __syncthreads();   // all slab-scratch reads done before S5 overwrites

  // ---------------- S5: bn+relu, Iin into LDS rows [h][RS]
  {
    float ca[H];
#pragma unroll
    for (int j = 0; j < H; ++j)
      ca[j] = fmaxf(p.g_c[j] * (pca[j] - stM[j]) * stI[j] + p.be_c[j], 0.f);
#pragma unroll
    for (int h = 0; h < H; ++h) {
      float a = 0.f;
#pragma unroll
      for (int j = 0; j < H; ++j) a = fmaf(ca[j], p.W_in[h * H + j], a);
      slab[h * RS + t0] = a;
    }
#pragma unroll
    for (int j = 0; j < H; ++j)
      ca[j] = fmaxf(p.g_c[j] * (pcb[j] - stM[j]) * stI[j] + p.be_c[j], 0.f);
#pragma unroll
    for (int h = 0; h < H; ++h) {
      float a = 0.f;
#pragma unroll
      for (int j = 0; j < H; ++j) a = fmaf(ca[j], p.W_in[h * H + j], a);
      slab[h * RS + t1] = a;
    }
  }
  __syncthreads();

  // ---------------- S6: LSNN scan, wave 0 only; AND-trick rec dot
  if (tid < 64) {
    // gtot closed form: .9^1024/.8^1024 underflow -> (5*1024 - 81 + 16)/1024
    const float gtot = 4.9365234375f;

    const int slot = lane < H ? lane : 0;   // inactive lanes broadcast row 0
    const float* row = slab + slot * RS;
    int wri[H];                             // W_rec row, pre-bitcast to int
#pragma unroll
    for (int j = 0; j < H; ++j)
      wri[j] = (lane < H) ? __float_as_int(p.W_rec[lane * H + j]) : 0;

    float cur = 0.f, vm = 0.f, S = 0.f;
    unsigned lo = 0u;   // spike bits 0..9 (uniform); bits >=10 never read

    auto step = [&](float iin, float gt) {
      float p01 = maskf(lo, 0, wri[0]) + maskf(lo, 1, wri[1]);
      float p23 = maskf(lo, 2, wri[2]) + maskf(lo, 3, wri[3]);
      float p45 = maskf(lo, 4, wri[4]) + maskf(lo, 5, wri[5]);
      float p67 = maskf(lo, 6, wri[6]) + maskf(lo, 7, wri[7]);
      float p89 = maskf(lo, 8, wri[8]) + maskf(lo, 9, wri[9]);
      float rec = ((p01 + p23) + (p45 + p67)) + p89;
      float i_jump = (cur + iin) + rec;
      float v_dec = fmaf(0.1f, i_jump - vm, vm);  // vm + 0.1*(i_jump - vm)
      cur = 0.8f * i_jump;                        // i_dec
      bool z = v_dec > 0.5f;
      vm = z ? 0.f : v_dec;
      S += z ? gt : 0.f;
      lo = (unsigned)__ballot(z);                 // lanes>=10 pollute only high bits
    };

    float4 iA = *(const float4*)&row[0];
    float4 iB = *(const float4*)&row[4];
    float4 gA = *(const float4*)&gtab[0], gB = *(const float4*)&gtab[4];

    for (int t8 = 0; t8 < T - 8; t8 += 8) {
      float4 iN1 = *(const float4*)&row[t8 + 8];
      float4 iN2 = *(const float4*)&row[t8 + 12];
      float4 gN1 = *(const float4*)&gtab[t8 + 8];
      float4 gN2 = *(const float4*)&gtab[t8 + 12];
      step(iA.x, gA.x); step(iA.y, gA.y); step(iA.z, gA.z); step(iA.w, gA.w);
      step(iB.x, gB.x); step(iB.y, gB.y); step(iB.z, gB.z); step(iB.w, gB.w);
      iA = iN1; iB = iN2; gA = gN1; gB = gN2;
    }
    step(iA.x, gA.x); step(iA.y, gA.y); step(iA.z, gA.z); step(iA.w, gA.w);
    step(iB.x, gB.x); step(iB.y, gB.y); step(iB.z, gB.z); step(iB.w, gB.w);

    int li = lane < H ? lane : 0;
    float c0 = (lane < H) ? S * p.W_cls[li]     : 0.f;
    float c1 = (lane < H) ? S * p.W_cls[H + li] : 0.f;
    float r0 = wred63(c0), r1 = wred63(c1);
    if (lane == 63) {
      p.out[b * 2 + 0] = r0 + gtot * p.b_cls[0];
      p.out[b * 2 + 1] = r1 + gtot * p.b_cls[1];
    }
  }
}

extern "C" void kernel_launch(void* const* d_in, const int* in_sizes, int n_in,
                              void* d_out, int out_size, void* d_ws, size_t ws_size,
                              hipStream_t stream) {
  Params p;
  p.beeg  = (const float*)d_in[2];
  p.W_ef  = (const float*)d_in[4];
  p.b_ef  = (const float*)d_in[5];
  p.g_i   = (const float*)d_in[6];
  p.be_i  = (const float*)d_in[7];
  p.Wq    = (const float*)d_in[8];
  p.g_q   = (const float*)d_in[9];
  p.be_q  = (const float*)d_in[10];
  p.Wk    = (const float*)d_in[11];
  p.g_k   = (const float*)d_in[12];
  p.be_k  = (const float*)d_in[13];
  p.Wv    = (const float*)d_in[14];
  p.g_v   = (const float*)d_in[15];
  p.be_v  = (const float*)d_in[16];
  p.Wc    = (const float*)d_in[17];
  p.g_c   = (const float*)d_in[18];
  p.be_c  = (const float*)d_in[19];
  p.W_in  = (const float*)d_in[20];
  p.W_rec = (const float*)d_in[21];
  p.W_cls = (const float*)d_in[22];
  p.b_cls = (const float*)d_in[23];

  char* ws = (char*)d_ws;
  p.cnt = (int*)ws;                            // 3 counters, memset below
  p.P1  = (double*)(ws + 256);                 // [20][32] doubles
  p.P2  = (double*)(ws + 256 + 5120);          // [60][32] doubles
  p.P3  = (double*)(ws + 256 + 5120 + 15360);  // [20][32] doubles
  p.out = (float*)d_out;

  (void)hipMemsetAsync(d_ws, 0, 256, stream);  // zero barrier counters
  fused12<<<dim3(B), dim3(NT), 0, stream>>>(p);
}